// Round 1
// 101.668 us; speedup vs baseline: 1.0170x; 1.0170x over previous
//
#include <hip/hip_runtime.h>

// DifferentiableCensus: out[i,j] = (1/9) * sum_{3x3, edge-clamped} sigmoid(x[nb] - x[c])
// x: (16,3,512,512) f32 = 48 planes of 512x512.
//
// Pair-sharing identity: sigmoid(a-b) = 1 - sigmoid(b-a) -> 19 sigmoids per
// 4-wide output row instead of 32 (E/S/SE/SW pairs shared; center = 0.5).
//
// v2 changes vs previous best:
//  * Neighbor columns via wave shuffles: lane i's left/right halo values are
//    lane (i-1).v.w / lane (i+1).v.x (waves cover 64 consecutive 4-col
//    segments of one row band). Replaces 2 stride-16B scalar loads per row
//    (16 L1 lines each!) with 2 ds_bpermute + one 2-active-lane edge load.
//  * Distance-2 row streaming: raw float4 rows are prefetched one full
//    iteration (19 sigmoids) before the shuffle+scale+consume, so the
//    per-row vmcnt stall of the old "load nxt, use nxt" pattern is gone.

#define CENSUS_H 512
#define CENSUS_W 512
#define ROWS_PER_THREAD 8

#if __has_builtin(__builtin_amdgcn_exp2f)
#define FAST_EXP2(v) __builtin_amdgcn_exp2f(v)
#else
#define FAST_EXP2(v) exp2f(v)
#endif

#if __has_builtin(__builtin_amdgcn_rcpf)
#define FAST_RCP(v) __builtin_amdgcn_rcpf(v)
#else
#define FAST_RCP(v) (1.0f / (v))
#endif

// Inputs are pre-scaled by log2(e): sigmoid(a-b) = 1/(1+exp2(b_s - a_s)).
__device__ __forceinline__ float sigdiff(float a_s, float b_s) {
    float e = FAST_EXP2(b_s - a_s);
    return FAST_RCP(1.0f + e);
}

__global__ __launch_bounds__(256) void census_kernel(const float* __restrict__ x,
                                                     float* __restrict__ out) {
    const float L2E = 1.44269504088896340736f;  // log2(e)

    int g = blockIdx.x * 256 + threadIdx.x;
    int lane   = threadIdx.x & 63;
    int colseg = g & 127;          // 128 segments of 4 cols = 512
    int band   = (g >> 7) & 63;    // 64 bands of 8 rows = 512
    int plane  = g >> 13;          // 48 planes

    int j0 = colseg << 2;
    int i0 = band << 3;
    int jl = (j0 > 0) ? j0 - 1 : 0;
    int jr = (j0 + 4 < CENSUS_W) ? j0 + 4 : CENSUS_W - 1;
    // Only wave-edge lanes need a real halo load (clamped addr makes the
    // j0==0 / j0==508 cases come out right automatically).
    const int  jc   = (lane == 0) ? jl : jr;
    const bool edge = (lane == 0) || (lane == 63);

    const float* P = x + (size_t)plane * (CENSUS_H * CENSUS_W);
    float* O = out + (size_t)plane * (CENSUS_H * CENSUS_W) + (size_t)i0 * CENSUS_W + j0;

    float4 fb[3];                 // raw row quads, rotating (indices static after unroll)
    float  eb[3] = {0.f, 0.f, 0.f};  // halo value, valid only in lanes 0/63

    auto FETCH = [&](int row, int s) {
        const float* rp = P + (size_t)row * CENSUS_W;
        fb[s] = *reinterpret_cast<const float4*>(rp + j0);
        if (edge) eb[s] = rp[jc];   // 2 active lanes -> 1-2 cache lines
    };

    float cur[6], nxt[6], acc[4];

    auto UNPACK = [&](int s, float* d) {
        float4 v = fb[s];
        float ax = v.x * L2E, ay = v.y * L2E, az = v.z * L2E, aw = v.w * L2E;
        float es = eb[s] * L2E;
        float lf = __shfl_up(aw, 1);     // left lane's col j0-1 (already scaled)
        float rt = __shfl_down(ax, 1);   // right lane's col j0+4
        lf = (lane == 0)  ? es : lf;     // cndmask, branchless
        rt = (lane == 63) ? es : rt;
        d[0] = lf; d[1] = ax; d[2] = ay; d[3] = az; d[4] = aw; d[5] = rt;
    };

    // ---- prologue: rows i0-1 (clamped), i0, i0+1 ----
    int rm1 = (i0 > 0) ? i0 - 1 : 0;
    FETCH(rm1,    0);
    FETCH(i0,     1);
    FETCH(i0 + 1, 2);   // i0+1 <= 505 < 512, never needs clamping

    UNPACK(0, cur);     // row i0-1
    UNPACK(1, nxt);     // row i0

    // ---- init acc for row i0: N/NW/NE complements from pair (i0-1, i0) ----
#pragma unroll
    for (int k = 0; k < 4; ++k) {
        float sv = sigdiff(nxt[k + 1], cur[k + 1]);
        float sd = sigdiff(nxt[k + 1], cur[k]);
        float sb = sigdiff(nxt[k + 1], cur[k + 2]);
        acc[k] = 3.0f - sv - sd - sb;
    }
#pragma unroll
    for (int t = 0; t < 6; ++t) cur[t] = nxt[t];   // cur = row i0

    // ---- stream 8 output rows; prefetch row r+2 while consuming row r+1 ----
#pragma unroll
    for (int r = 0; r < ROWS_PER_THREAD; ++r) {
        if (r < ROWS_PER_THREAD - 1) {
            int prow = i0 + r + 2;
            if (prow > CENSUS_H - 1) prow = CENSUS_H - 1;
            FETCH(prow, r % 3);            // overwrites slot of dead row r-1
        }
        UNPACK((r + 2) % 3, nxt);          // row i0+r+1, fetched 1 iter ago

        float se[5], sv[4], sd[5], sb[5];
#pragma unroll
        for (int t = 0; t < 5; ++t) se[t] = sigdiff(cur[t + 1], cur[t]);
#pragma unroll
        for (int k = 0; k < 4; ++k) sv[k] = sigdiff(nxt[k + 1], cur[k + 1]);
#pragma unroll
        for (int t = 0; t < 5; ++t) sd[t] = sigdiff(nxt[t + 1], cur[t]);
#pragma unroll
        for (int t = 0; t < 5; ++t) sb[t] = sigdiff(nxt[t], cur[t + 1]);

        float o[4];
#pragma unroll
        for (int k = 0; k < 4; ++k) {
            // C + E + W + S + SE + SW  (N/NW/NE already in acc[k])
            float a = acc[k] + 1.5f;        // +0.5 center, +1 for the (1-se[k]) W tap
            a += se[k + 1] - se[k];         // E + (W - 1)
            a += sv[k] + sd[k + 1] + sb[k];
            o[k] = a * (1.0f / 9.0f);
            // seed next row's acc: N + NW + NE complements
            acc[k] = 3.0f - sv[k] - sd[k] - sb[k + 1];
        }
        *reinterpret_cast<float4*>(O + (size_t)r * CENSUS_W) =
            make_float4(o[0], o[1], o[2], o[3]);

#pragma unroll
        for (int t = 0; t < 6; ++t) cur[t] = nxt[t];
    }
}

extern "C" void kernel_launch(void* const* d_in, const int* in_sizes, int n_in,
                              void* d_out, int out_size, void* d_ws, size_t ws_size,
                              hipStream_t stream) {
    const float* x = (const float*)d_in[0];
    float* out = (float*)d_out;

    // 48 planes * 64 bands * 128 colsegs = 393216 threads
    int n_threads = (in_sizes[0] / (CENSUS_W * CENSUS_H)) * 64 * 128;
    int block = 256;
    int grid = (n_threads + block - 1) / block;

    census_kernel<<<grid, block, 0, stream>>>(x, out);
}